// Round 4
// baseline (1803.836 us; speedup 1.0000x reference)
//
#include <hip/hip_runtime.h>
#include <hip/hip_bf16.h>

// ByteTransformer forward on MI355X (gfx950).
// L=8, E=1024, M=4096, H=16, C=64, T=1024, B=2, V=128. Rows = B*T = 2048.
// R4: GEMM K-loop -> 3-buffer, distance-2 pipeline with raw s_barrier +
// counted s_waitcnt vmcnt(8/4/0) (T4). Loads stay in flight across barriers;
// never drain vmcnt to 0 in the main loop.

typedef __bf16 bf16x8 __attribute__((ext_vector_type(8)));
typedef __bf16 bf16x4 __attribute__((ext_vector_type(4)));
typedef float  f32x4  __attribute__((ext_vector_type(4)));

#define DEV __device__ __forceinline__

DEV void load_lds16(const void* g, void* l) {
  __builtin_amdgcn_global_load_lds((const __attribute__((address_space(1))) void*)g,
                                   (__attribute__((address_space(3))) void*)l,
                                   16, 0, 0);
}

// ---------------- embedding: x[row,e] = W_tok[e, byte] + W_pos[e, t] ----------------
__global__ __launch_bounds__(256) void embed_k(const int* __restrict__ bytes,
                                               const float* __restrict__ Wtok,
                                               const float* __restrict__ Wpos,
                                               float* __restrict__ x) {
  const int row = blockIdx.x;          // b*1024 + t
  const int t = row & 1023;
  const int byte = bytes[row];
  const int e0 = threadIdx.x * 4;
  f32x4 v;
#pragma unroll
  for (int j = 0; j < 4; ++j)
    v[j] = Wtok[(e0 + j) * 128 + byte] + Wpos[(e0 + j) * 1024 + t];
  *(f32x4*)(x + (long)row * 1024 + e0) = v;
}

// ---------------- f32 -> bf16 converters ----------------
__global__ __launch_bounds__(256) void cvt_k(const float* __restrict__ in,
                                             __bf16* __restrict__ out, int n4) {
  int i = blockIdx.x * 256 + threadIdx.x;
  if (i >= n4) return;
  f32x4 v = ((const f32x4*)in)[i];
  bf16x4 o = {(__bf16)v[0], (__bf16)v[1], (__bf16)v[2], (__bf16)v[3]};
  ((bf16x4*)out)[i] = o;
}

// convert one layer's Wqkv (3072x1024), W1 (4096x1024), W2 (1024x4096)
__global__ __launch_bounds__(256) void cvt3_k(const float* __restrict__ a,
                                              const float* __restrict__ b,
                                              const float* __restrict__ c,
                                              __bf16* __restrict__ oa,
                                              __bf16* __restrict__ ob,
                                              __bf16* __restrict__ oc) {
  int i = blockIdx.x * 256 + threadIdx.x;   // float4 index over 2883584 total
  const float* s; __bf16* d; int off;
  if (i < 786432)                { s = a; d = oa; off = i; }
  else if (i < 786432 + 1048576) { s = b; d = ob; off = i - 786432; }
  else                           { s = c; d = oc; off = i - (786432 + 1048576); }
  f32x4 v = ((const f32x4*)s)[off];
  bf16x4 o = {(__bf16)v[0], (__bf16)v[1], (__bf16)v[2], (__bf16)v[3]};
  ((bf16x4*)d)[off] = o;
}

// ---------------- LayerNorm (row = 1024 f32). ADD: v = x + y, also writes xb=v ----------------
template <bool ADD>
__global__ __launch_bounds__(256) void ln_k(const float* __restrict__ xin,
                                            const float* __restrict__ yin,
                                            const float* __restrict__ g,
                                            const float* __restrict__ be,
                                            __bf16* __restrict__ hout,
                                            float* __restrict__ xbout) {
  const int row = blockIdx.x, tid = threadIdx.x;
  f32x4 v = ((const f32x4*)(xin + (long)row * 1024))[tid];
  if (ADD) v += ((const f32x4*)(yin + (long)row * 1024))[tid];
  float s  = v[0] + v[1] + v[2] + v[3];
  float ss = v[0]*v[0] + v[1]*v[1] + v[2]*v[2] + v[3]*v[3];
#pragma unroll
  for (int d = 1; d < 64; d <<= 1) { s += __shfl_xor(s, d, 64); ss += __shfl_xor(ss, d, 64); }
  __shared__ float red[4][2];
  const int w = tid >> 6;
  if ((tid & 63) == 0) { red[w][0] = s; red[w][1] = ss; }
  __syncthreads();
  s  = red[0][0] + red[1][0] + red[2][0] + red[3][0];
  ss = red[0][1] + red[1][1] + red[2][1] + red[3][1];
  const float mu  = s * (1.f / 1024.f);
  const float var = ss * (1.f / 1024.f) - mu * mu;
  const float rstd = rsqrtf(var + 1e-5f);
  f32x4 gv = ((const f32x4*)g)[tid];
  f32x4 bv = ((const f32x4*)be)[tid];
  f32x4 nv = (v - mu) * rstd * gv + bv;
  bf16x4 o = {(__bf16)nv[0], (__bf16)nv[1], (__bf16)nv[2], (__bf16)nv[3]};
  ((bf16x4*)(hout + (long)row * 1024))[tid] = o;
  if (ADD) ((f32x4*)(xbout + (long)row * 1024))[tid] = v;
}

// ---------------- GEMM: out[r,n] = sum_k A[r,k]*Bw[n,k]  (both K-contiguous, bf16) ----
// 128x128 tile, BK=32, 4 waves (2x2 of 64x64), 16x16x32 MFMA.
// 3-buffer distance-2 pipeline: STAGE(t+2) -> vmcnt(8) -> barrier -> MFMA(t)
// -> barrier. Counted vmcnt keeps 8 loads in flight across barriers (T4).
// EPI: 0 = bf16 out; 1 = bias+relu -> bf16; 2 = f32 partial[bz] (split-K).
template <int EPI, int SPLITK>
__global__ __launch_bounds__(256) void gemm_k(const __bf16* __restrict__ A,
                                              const __bf16* __restrict__ Bw,
                                              const float* __restrict__ bias,
                                              __bf16* __restrict__ outb,
                                              float* __restrict__ partial,
                                              int M, int N, int K) {
  const int tid = threadIdx.x;
  const int w = tid >> 6, l = tid & 63;
  const int bm = blockIdx.x, bn = blockIdx.y, bz = blockIdx.z;
  __shared__ __align__(16) __bf16 lA[3][4096];   // [buf][128][32]
  __shared__ __align__(16) __bf16 lB[3][4096];
  const f32x4 zero = {0.f, 0.f, 0.f, 0.f};
  f32x4 acc[4][4];
#pragma unroll
  for (int a = 0; a < 4; ++a)
#pragma unroll
    for (int b = 0; b < 4; ++b) acc[a][b] = zero;
  const int Kc = K / SPLITK;
  const int nt = Kc / 32;                 // 32 or 8 K-steps
  const int srow = w * 16 + (l >> 2);
  const int scol = (l & 3) * 8;
  const __bf16* Ap = A + (long)(bm * 128 + srow) * K + bz * Kc + scol;
  const __bf16* Bp = Bw + (long)(bn * 128 + srow) * K + bz * Kc + scol;
  const long rstr = (long)64 * K;
  const int lwoff = w * 512;              // wave-uniform LDS dest base (lane*16B auto)
  const int lr = l & 15;
  const int kk = (l >> 4) * 8;
  const int mrow = (w >> 1) * 64, ncol = (w & 1) * 64;

#define STAGE(buf, kt)                                            \
  do {                                                            \
    load_lds16(Ap + (kt), &lA[buf][lwoff]);                       \
    load_lds16(Ap + (kt) + rstr, &lA[buf][lwoff + 2048]);         \
    load_lds16(Bp + (kt), &lB[buf][lwoff]);                       \
    load_lds16(Bp + (kt) + rstr, &lB[buf][lwoff + 2048]);         \
  } while (0)

#define COMPUTE(b)                                                             \
  do {                                                                         \
    bf16x8 af[4], bfv[4];                                                      \
    _Pragma("unroll")                                                          \
    for (int mi = 0; mi < 4; ++mi)                                             \
      af[mi] = *(const bf16x8*)&lA[b][(mrow + mi * 16 + lr) * 32 + kk];        \
    _Pragma("unroll")                                                          \
    for (int ni = 0; ni < 4; ++ni)                                             \
      bfv[ni] = *(const bf16x8*)&lB[b][(ncol + ni * 16 + lr) * 32 + kk];       \
    _Pragma("unroll")                                                          \
    for (int mi = 0; mi < 4; ++mi)                                             \
      _Pragma("unroll")                                                        \
      for (int ni = 0; ni < 4; ++ni)                                           \
        acc[mi][ni] = __builtin_amdgcn_mfma_f32_16x16x32_bf16(af[mi], bfv[ni], \
                                                              acc[mi][ni], 0, 0, 0); \
  } while (0)

  STAGE(0, 0);
  STAGE(1, 32);
  int rb = 0;   // read buffer
  int sb = 2;   // stage buffer
  for (int t = 0; t < nt - 2; ++t) {
    STAGE(sb, (t + 2) * 32);
    sb = (sb == 2) ? 0 : sb + 1;
    asm volatile("s_waitcnt vmcnt(8)" ::: "memory");  // oldest tile landed; 8 stay in flight
    __builtin_amdgcn_s_barrier();                     // publish DMA to all waves
    COMPUTE(rb);
    rb = (rb == 2) ? 0 : rb + 1;
    __builtin_amdgcn_s_barrier();                     // reads done before next STAGE overwrites
  }
  asm volatile("s_waitcnt vmcnt(4)" ::: "memory");
  __builtin_amdgcn_s_barrier();
  COMPUTE(rb);
  rb = (rb == 2) ? 0 : rb + 1;
  asm volatile("s_waitcnt vmcnt(0)" ::: "memory");
  __builtin_amdgcn_s_barrier();
  COMPUTE(rb);
#undef STAGE
#undef COMPUTE
  // epilogue: D[row=(l>>4)*4+i, col=l&15] per 16x16 fragment (m89-verified layout)
#pragma unroll
  for (int mi = 0; mi < 4; ++mi)
#pragma unroll
    for (int ni = 0; ni < 4; ++ni)
#pragma unroll
      for (int i = 0; i < 4; ++i) {
        const int r = bm * 128 + mrow + mi * 16 + (l >> 4) * 4 + i;
        const int c = bn * 128 + ncol + ni * 16 + lr;
        float v = acc[mi][ni][i];
        if (EPI == 0) {
          outb[(long)r * N + c] = (__bf16)v;
        } else if (EPI == 1) {
          v += bias[c];
          v = fmaxf(v, 0.f);
          outb[(long)r * N + c] = (__bf16)v;
        } else {
          partial[((long)bz * M + r) * N + c] = v;
        }
      }
}

// ---------------- flash attention (causal). qkv row: [h*192 + {q:0,k:64,v:128} + c] ----
// block = (q-tile of 64 rows) x (b,h). 4 waves x 16 q-rows. K/V tiles of 32.
__global__ __launch_bounds__(256) void attn_k(const __bf16* __restrict__ qkv,
                                              float* __restrict__ y) {
  const int qt = blockIdx.x;            // 0..15
  const int bh = blockIdx.y;            // 0..31
  const int bI = bh >> 4, h = bh & 15;
  const int tid = threadIdx.x, w = tid >> 6, l = tid & 63;
  const int lr = l & 15, kg = l >> 4;
  __shared__ __align__(16) __bf16 lK[32 * 64];     // [s][c]
  __shared__ __align__(16) __bf16 lV[64 * 32];     // [c][s]  (transposed)
  __shared__ __align__(16) __bf16 lP[4][16 * 32];  // per-wave P tile
  const long base = (long)bI * 1024 * 3072;
  const __bf16* qp = qkv + base + (long)(qt * 64 + w * 16 + lr) * 3072 + h * 192;
  const bf16x8 qf0 = *(const bf16x8*)(qp + kg * 8);
  const bf16x8 qf1 = *(const bf16x8*)(qp + 32 + kg * 8);
  const f32x4 zero = {0.f, 0.f, 0.f, 0.f};
  f32x4 o[4] = {zero, zero, zero, zero};
  float mrow[4] = {-1e30f, -1e30f, -1e30f, -1e30f};
  float lsum[4] = {0.f, 0.f, 0.f, 0.f};
  const int qg = qt * 64 + w * 16 + kg * 4;
  const int nkt = 2 * qt + 2;
  const int srow = tid >> 3, sc = (tid & 7) * 8;
  for (int it = 0; it < nkt; ++it) {
    const int kt = it * 32;
    __syncthreads();   // K/V LDS free from previous iteration's readers
    {
      const __bf16* kp = qkv + base + (long)(kt + srow) * 3072 + h * 192 + 64 + sc;
      *(f32x4*)&lK[srow * 64 + sc] = *(const f32x4*)kp;   // K row-major
      bf16x8 vv = *(const bf16x8*)(kp + 64);              // V, transpose into lV
#pragma unroll
      for (int j = 0; j < 8; ++j) lV[(sc + j) * 32 + srow] = vv[j];
    }
    __syncthreads();
    // S = q . k^T   (two 16-col fragments, K=64 via 2 MFMAs each)
    f32x4 s0 = zero, s1 = zero;
    {
      bf16x8 k00 = *(const bf16x8*)&lK[lr * 64 + kg * 8];
      bf16x8 k01 = *(const bf16x8*)&lK[lr * 64 + 32 + kg * 8];
      s0 = __builtin_amdgcn_mfma_f32_16x16x32_bf16(qf0, k00, s0, 0, 0, 0);
      s0 = __builtin_amdgcn_mfma_f32_16x16x32_bf16(qf1, k01, s0, 0, 0, 0);
      bf16x8 k10 = *(const bf16x8*)&lK[(16 + lr) * 64 + kg * 8];
      bf16x8 k11 = *(const bf16x8*)&lK[(16 + lr) * 64 + 32 + kg * 8];
      s1 = __builtin_amdgcn_mfma_f32_16x16x32_bf16(qf0, k10, s1, 0, 0, 0);
      s1 = __builtin_amdgcn_mfma_f32_16x16x32_bf16(qf1, k11, s1, 0, 0, 0);
    }
    // online softmax; D layout: row = kg*4+i, col = lr
#pragma unroll
    for (int i = 0; i < 4; ++i) {
      float a = s0[i] * 0.125f, b = s1[i] * 0.125f;
      const int q_i = qg + i;
      if (kt + lr > q_i)      a = -1e30f;
      if (kt + 16 + lr > q_i) b = -1e30f;
      float mx = fmaxf(a, b);
#pragma unroll
      for (int d = 1; d < 16; d <<= 1) mx = fmaxf(mx, __shfl_xor(mx, d, 64));
      const float mn = fmaxf(mrow[i], mx);
      const float scl = __expf(mrow[i] - mn);
      const float p0 = __expf(a - mn);
      const float p1 = __expf(b - mn);
      float ps = p0 + p1;
#pragma unroll
      for (int d = 1; d < 16; d <<= 1) ps += __shfl_xor(ps, d, 64);
      lsum[i] = lsum[i] * scl + ps;
      mrow[i] = mn;
      o[0][i] *= scl; o[1][i] *= scl; o[2][i] *= scl; o[3][i] *= scl;
      lP[w][(kg * 4 + i) * 32 + lr] = (__bf16)p0;
      lP[w][(kg * 4 + i) * 32 + 16 + lr] = (__bf16)p1;
    }
    // P (A-frag) x V  -> O   (per-wave LDS region; compiler orders ds write->read)
    bf16x8 pf = *(const bf16x8*)&lP[w][lr * 32 + kg * 8];
#pragma unroll
    for (int cf = 0; cf < 4; ++cf) {
      bf16x8 vf = *(const bf16x8*)&lV[(cf * 16 + lr) * 32 + kg * 8];
      o[cf] = __builtin_amdgcn_mfma_f32_16x16x32_bf16(pf, vf, o[cf], 0, 0, 0);
    }
  }
  float* yp = y + ((long)bI * 1024 + qt * 64 + w * 16 + kg * 4) * 1024 + h * 64 + lr;
#pragma unroll
  for (int i = 0; i < 4; ++i) {
    const float inv = 1.0f / lsum[i];
#pragma unroll
    for (int cf = 0; cf < 4; ++cf)
      yp[(long)i * 1024 + cf * 16] = o[cf][i] * inv;
  }
}

// ---------------- reduces ----------------
// x = x + xb + b2[c] + sum_z partial[z]   (2048x1024, float4)
__global__ __launch_bounds__(256) void red_mlp_k(const float* __restrict__ part,
                                                 float* __restrict__ x,
                                                 const float* __restrict__ xb,
                                                 const float* __restrict__ b2) {
  const int i = blockIdx.x * 256 + threadIdx.x;  // 0..524287
  const f32x4* p = (const f32x4*)part;
  f32x4 v = ((const f32x4*)x)[i] + ((const f32x4*)xb)[i] + ((const f32x4*)b2)[i & 255]
          + p[i] + p[i + 524288] + p[i + 2 * 524288] + p[i + 3 * 524288];
  ((f32x4*)x)[i] = v;
}

// out = b_out[c] + sum_z partial[z]   (2048x128, float4)
__global__ __launch_bounds__(256) void red_out_k(const float* __restrict__ part,
                                                 const float* __restrict__ bo,
                                                 float* __restrict__ out) {
  const int i = blockIdx.x * 256 + threadIdx.x;  // 0..65535
  const f32x4* p = (const f32x4*)part;
  f32x4 v = ((const f32x4*)bo)[i & 31]
          + p[i] + p[i + 65536] + p[i + 2 * 65536] + p[i + 3 * 65536];
  ((f32x4*)out)[i] = v;
}

// ---------------- driver ----------------
extern "C" void kernel_launch(void* const* d_in, const int* in_sizes, int n_in,
                              void* d_out, int out_size, void* d_ws, size_t ws_size,
                              hipStream_t stream) {
  (void)in_sizes; (void)n_in; (void)out_size; (void)ws_size;
  const int*   bytes = (const int*)  d_in[0];
  const float* Wtok  = (const float*)d_in[1];
  const float* Wpos  = (const float*)d_in[2];
  const float* Wqkv  = (const float*)d_in[3];
  const float* ln1g  = (const float*)d_in[4];
  const float* ln1b  = (const float*)d_in[5];
  const float* ln2g  = (const float*)d_in[6];
  const float* ln2b  = (const float*)d_in[7];
  const float* W1    = (const float*)d_in[8];
  const float* b1    = (const float*)d_in[9];
  const float* W2    = (const float*)d_in[10];
  const float* b2    = (const float*)d_in[11];
  const float* lnfg  = (const float*)d_in[12];
  const float* lnfb  = (const float*)d_in[13];
  const float* Wout  = (const float*)d_in[14];
  const float* bout  = (const float*)d_in[15];
  float* out = (float*)d_out;

  // workspace carve (total ~110.3 MB)
  char* ws = (char*)d_ws;
  float*  x    = (float*) (ws + 0);         //  8 MB  f32 residual stream
  float*  xb   = (float*) (ws + 8388608);   //  8 MB  f32 x + attn
  float*  yb   = (float*) (ws + 16777216);  //  8 MB  f32 attention out
  __bf16* h    = (__bf16*)(ws + 25165824);  //  4 MB  bf16 LN output
  __bf16* qkv  = (__bf16*)(ws + 29360128);  // 12 MB  bf16 qkv
  __bf16* mb   = (__bf16*)(ws + 41943040);  // 16 MB  bf16 MLP hidden
  __bf16* wqb  = (__bf16*)(ws + 58720256);  //  6 MB  bf16 Wqkv (layer)
  __bf16* w1b  = (__bf16*)(ws + 65011712);  //  8 MB  bf16 W1 (layer)
  __bf16* w2b  = (__bf16*)(ws + 73400320);  //  8 MB  bf16 W2 (layer)
  __bf16* wob  = (__bf16*)(ws + 81788928);  // .25 MB bf16 W_out
  float*  part = (float*) (ws + 82051072);  // 32 MB  f32 split-K partials

  embed_k<<<2048, 256, 0, stream>>>(bytes, Wtok, Wpos, x);
  cvt_k<<<128, 256, 0, stream>>>(Wout, wob, 32768);
  for (int lay = 0; lay < 8; ++lay) {
    cvt3_k<<<11264, 256, 0, stream>>>(Wqkv + (long)lay * 3145728,
                                      W1 + (long)lay * 4194304,
                                      W2 + (long)lay * 4194304, wqb, w1b, w2b);
    ln_k<false><<<2048, 256, 0, stream>>>(x, nullptr, ln1g + lay * 1024, ln1b + lay * 1024, h, nullptr);
    gemm_k<0, 1><<<dim3(16, 24, 1), 256, 0, stream>>>(h, wqb, nullptr, qkv, nullptr, 2048, 3072, 1024);
    attn_k<<<dim3(16, 32, 1), 256, 0, stream>>>(qkv, yb);
    ln_k<true><<<2048, 256, 0, stream>>>(x, yb, ln2g + lay * 1024, ln2b + lay * 1024, h, xb);
    gemm_k<1, 1><<<dim3(16, 32, 1), 256, 0, stream>>>(h, w1b, b1 + lay * 4096, mb, nullptr, 2048, 4096, 1024);
    gemm_k<2, 4><<<dim3(16, 8, 4), 256, 0, stream>>>(mb, w2b, nullptr, nullptr, part, 2048, 1024, 4096);
    red_mlp_k<<<2048, 256, 0, stream>>>(part, x, xb, b2 + lay * 1024);
  }
  ln_k<false><<<2048, 256, 0, stream>>>(x, nullptr, lnfg, lnfb, h, nullptr);
  gemm_k<2, 4><<<dim3(16, 1, 4), 256, 0, stream>>>(h, wob, nullptr, nullptr, part, 2048, 128, 1024);
  red_out_k<<<256, 256, 0, stream>>>(part, bout, out);
}

// Round 5
// 1746.262 us; speedup vs baseline: 1.0330x; 1.0330x over previous
//
#include <hip/hip_runtime.h>
#include <hip/hip_bf16.h>

// ByteTransformer forward on MI355X (gfx950).
// L=8, E=1024, M=4096, H=16, C=64, T=1024, B=2, V=128. Rows = B*T = 2048.
// R5: revert GEMM sync to R3's clean 2-phase dbuf (R4's counted-vmcnt was
// null + pathological under profiling). New lever: 128x64 tiles (acc[4][2],
// 4 waves of 64x32) -> grids 768/1024/1024 blocks = 3-4 blocks/CU, so
// inter-block wave overlap hides the barrier drain (m114/m102 regime).

typedef __bf16 bf16x8 __attribute__((ext_vector_type(8)));
typedef __bf16 bf16x4 __attribute__((ext_vector_type(4)));
typedef float  f32x4  __attribute__((ext_vector_type(4)));

#define DEV __device__ __forceinline__

DEV void load_lds16(const void* g, void* l) {
  __builtin_amdgcn_global_load_lds((const __attribute__((address_space(1))) void*)g,
                                   (__attribute__((address_space(3))) void*)l,
                                   16, 0, 0);
}

// ---------------- embedding: x[row,e] = W_tok[e, byte] + W_pos[e, t] ----------------
__global__ __launch_bounds__(256) void embed_k(const int* __restrict__ bytes,
                                               const float* __restrict__ Wtok,
                                               const float* __restrict__ Wpos,
                                               float* __restrict__ x) {
  const int row = blockIdx.x;          // b*1024 + t
  const int t = row & 1023;
  const int byte = bytes[row];
  const int e0 = threadIdx.x * 4;
  f32x4 v;
#pragma unroll
  for (int j = 0; j < 4; ++j)
    v[j] = Wtok[(e0 + j) * 128 + byte] + Wpos[(e0 + j) * 1024 + t];
  *(f32x4*)(x + (long)row * 1024 + e0) = v;
}

// ---------------- f32 -> bf16 converters ----------------
__global__ __launch_bounds__(256) void cvt_k(const float* __restrict__ in,
                                             __bf16* __restrict__ out, int n4) {
  int i = blockIdx.x * 256 + threadIdx.x;
  if (i >= n4) return;
  f32x4 v = ((const f32x4*)in)[i];
  bf16x4 o = {(__bf16)v[0], (__bf16)v[1], (__bf16)v[2], (__bf16)v[3]};
  ((bf16x4*)out)[i] = o;
}

// convert one layer's Wqkv (3072x1024), W1 (4096x1024), W2 (1024x4096)
__global__ __launch_bounds__(256) void cvt3_k(const float* __restrict__ a,
                                              const float* __restrict__ b,
                                              const float* __restrict__ c,
                                              __bf16* __restrict__ oa,
                                              __bf16* __restrict__ ob,
                                              __bf16* __restrict__ oc) {
  int i = blockIdx.x * 256 + threadIdx.x;   // float4 index over 2883584 total
  const float* s; __bf16* d; int off;
  if (i < 786432)                { s = a; d = oa; off = i; }
  else if (i < 786432 + 1048576) { s = b; d = ob; off = i - 786432; }
  else                           { s = c; d = oc; off = i - (786432 + 1048576); }
  f32x4 v = ((const f32x4*)s)[off];
  bf16x4 o = {(__bf16)v[0], (__bf16)v[1], (__bf16)v[2], (__bf16)v[3]};
  ((bf16x4*)d)[off] = o;
}

// ---------------- LayerNorm (row = 1024 f32). ADD: v = x + y, also writes xb=v ----------------
template <bool ADD>
__global__ __launch_bounds__(256) void ln_k(const float* __restrict__ xin,
                                            const float* __restrict__ yin,
                                            const float* __restrict__ g,
                                            const float* __restrict__ be,
                                            __bf16* __restrict__ hout,
                                            float* __restrict__ xbout) {
  const int row = blockIdx.x, tid = threadIdx.x;
  f32x4 v = ((const f32x4*)(xin + (long)row * 1024))[tid];
  if (ADD) v += ((const f32x4*)(yin + (long)row * 1024))[tid];
  float s  = v[0] + v[1] + v[2] + v[3];
  float ss = v[0]*v[0] + v[1]*v[1] + v[2]*v[2] + v[3]*v[3];
#pragma unroll
  for (int d = 1; d < 64; d <<= 1) { s += __shfl_xor(s, d, 64); ss += __shfl_xor(ss, d, 64); }
  __shared__ float red[4][2];
  const int w = tid >> 6;
  if ((tid & 63) == 0) { red[w][0] = s; red[w][1] = ss; }
  __syncthreads();
  s  = red[0][0] + red[1][0] + red[2][0] + red[3][0];
  ss = red[0][1] + red[1][1] + red[2][1] + red[3][1];
  const float mu  = s * (1.f / 1024.f);
  const float var = ss * (1.f / 1024.f) - mu * mu;
  const float rstd = rsqrtf(var + 1e-5f);
  f32x4 gv = ((const f32x4*)g)[tid];
  f32x4 bv = ((const f32x4*)be)[tid];
  f32x4 nv = (v - mu) * rstd * gv + bv;
  bf16x4 o = {(__bf16)nv[0], (__bf16)nv[1], (__bf16)nv[2], (__bf16)nv[3]};
  ((bf16x4*)(hout + (long)row * 1024))[tid] = o;
  if (ADD) ((f32x4*)(xbout + (long)row * 1024))[tid] = v;
}

// ---------------- GEMM: out[r,n] = sum_k A[r,k]*Bw[n,k]  (both K-contiguous, bf16) ----
// 128(M)x64(N) tile, BK=32, 4 waves (2x2 of 64x32), 16x16x32 MFMA, acc[4][2].
// 2-phase double-buffered: STAGE(next) via global_load_lds(16) BEFORE MFMA(cur);
// one __syncthreads (vmcnt(0)+lgkmcnt(0)+barrier) per K-step.
// EPI: 0 = bf16 out; 1 = bias+relu -> bf16; 2 = f32 partial[bz] (split-K).
template <int EPI, int SPLITK>
__global__ __launch_bounds__(256) void gemm_k(const __bf16* __restrict__ A,
                                              const __bf16* __restrict__ Bw,
                                              const float* __restrict__ bias,
                                              __bf16* __restrict__ outb,
                                              float* __restrict__ partial,
                                              int M, int N, int K) {
  const int tid = threadIdx.x;
  const int w = tid >> 6, l = tid & 63;
  const int bm = blockIdx.x, bn = blockIdx.y, bz = blockIdx.z;
  __shared__ __align__(16) __bf16 lA[2][4096];   // [buf][128][32]
  __shared__ __align__(16) __bf16 lB[2][2048];   // [buf][ 64][32]
  const f32x4 zero = {0.f, 0.f, 0.f, 0.f};
  f32x4 acc[4][2];
#pragma unroll
  for (int a = 0; a < 4; ++a)
#pragma unroll
    for (int b = 0; b < 2; ++b) acc[a][b] = zero;
  const int Kc = K / SPLITK;
  const int srow = w * 16 + (l >> 2);     // staging row within a 64-row panel
  const int scol = (l & 3) * 8;
  const __bf16* Ap = A + (long)(bm * 128 + srow) * K + bz * Kc + scol;
  const __bf16* Bp = Bw + (long)(bn * 64 + srow) * K + bz * Kc + scol;
  const long rstr = (long)64 * K;
  const int lwoff = w * 512;              // wave-uniform LDS dest base (lane*16B auto)
  const int lr = l & 15;
  const int kk = (l >> 4) * 8;
  const int mrow = (w >> 1) * 64, ncol = (w & 1) * 32;   // wave quadrant: 64 x 32

#define STAGE(buf, kt)                                        \
  do {                                                        \
    load_lds16(Ap + (kt), &lA[buf][lwoff]);                   \
    load_lds16(Ap + (kt) + rstr, &lA[buf][lwoff + 2048]);     \
    load_lds16(Bp + (kt), &lB[buf][lwoff]);                   \
  } while (0)

  STAGE(0, 0);
  __syncthreads();
  int cur = 0;
  for (int kt = 0; kt < Kc; kt += 32) {
    if (kt + 32 < Kc) STAGE(cur ^ 1, kt + 32);   // prefetch flies during MFMA
    bf16x8 af[4], bfv[2];
#pragma unroll
    for (int mi = 0; mi < 4; ++mi) af[mi] = *(const bf16x8*)&lA[cur][(mrow + mi * 16 + lr) * 32 + kk];
#pragma unroll
    for (int ni = 0; ni < 2; ++ni) bfv[ni] = *(const bf16x8*)&lB[cur][(ncol + ni * 16 + lr) * 32 + kk];
#pragma unroll
    for (int mi = 0; mi < 4; ++mi)
#pragma unroll
      for (int ni = 0; ni < 2; ++ni)
        acc[mi][ni] = __builtin_amdgcn_mfma_f32_16x16x32_bf16(af[mi], bfv[ni], acc[mi][ni], 0, 0, 0);
    __syncthreads();          // drains vmcnt(0): next buffer ready; LDS reads retired
    cur ^= 1;
  }
#undef STAGE
  // epilogue: D[row=(l>>4)*4+i, col=l&15] per 16x16 fragment (m89-verified layout)
#pragma unroll
  for (int mi = 0; mi < 4; ++mi)
#pragma unroll
    for (int ni = 0; ni < 2; ++ni)
#pragma unroll
      for (int i = 0; i < 4; ++i) {
        const int r = bm * 128 + mrow + mi * 16 + (l >> 4) * 4 + i;
        const int c = bn * 64 + ncol + ni * 16 + lr;
        float v = acc[mi][ni][i];
        if (EPI == 0) {
          outb[(long)r * N + c] = (__bf16)v;
        } else if (EPI == 1) {
          v += bias[c];
          v = fmaxf(v, 0.f);
          outb[(long)r * N + c] = (__bf16)v;
        } else {
          partial[((long)bz * M + r) * N + c] = v;
        }
      }
}

// ---------------- flash attention (causal). qkv row: [h*192 + {q:0,k:64,v:128} + c] ----
// block = (q-tile of 64 rows) x (b,h). 4 waves x 16 q-rows. K/V tiles of 32.
__global__ __launch_bounds__(256) void attn_k(const __bf16* __restrict__ qkv,
                                              float* __restrict__ y) {
  const int qt = blockIdx.x;            // 0..15
  const int bh = blockIdx.y;            // 0..31
  const int bI = bh >> 4, h = bh & 15;
  const int tid = threadIdx.x, w = tid >> 6, l = tid & 63;
  const int lr = l & 15, kg = l >> 4;
  __shared__ __align__(16) __bf16 lK[32 * 64];     // [s][c]
  __shared__ __align__(16) __bf16 lV[64 * 32];     // [c][s]  (transposed)
  __shared__ __align__(16) __bf16 lP[4][16 * 32];  // per-wave P tile
  const long base = (long)bI * 1024 * 3072;
  const __bf16* qp = qkv + base + (long)(qt * 64 + w * 16 + lr) * 3072 + h * 192;
  const bf16x8 qf0 = *(const bf16x8*)(qp + kg * 8);
  const bf16x8 qf1 = *(const bf16x8*)(qp + 32 + kg * 8);
  const f32x4 zero = {0.f, 0.f, 0.f, 0.f};
  f32x4 o[4] = {zero, zero, zero, zero};
  float mrow[4] = {-1e30f, -1e30f, -1e30f, -1e30f};
  float lsum[4] = {0.f, 0.f, 0.f, 0.f};
  const int qg = qt * 64 + w * 16 + kg * 4;
  const int nkt = 2 * qt + 2;
  const int srow = tid >> 3, sc = (tid & 7) * 8;
  for (int it = 0; it < nkt; ++it) {
    const int kt = it * 32;
    __syncthreads();   // K/V LDS free from previous iteration's readers
    {
      const __bf16* kp = qkv + base + (long)(kt + srow) * 3072 + h * 192 + 64 + sc;
      *(f32x4*)&lK[srow * 64 + sc] = *(const f32x4*)kp;   // K row-major
      bf16x8 vv = *(const bf16x8*)(kp + 64);              // V, transpose into lV
#pragma unroll
      for (int j = 0; j < 8; ++j) lV[(sc + j) * 32 + srow] = vv[j];
    }
    __syncthreads();
    // S = q . k^T   (two 16-col fragments, K=64 via 2 MFMAs each)
    f32x4 s0 = zero, s1 = zero;
    {
      bf16x8 k00 = *(const bf16x8*)&lK[lr * 64 + kg * 8];
      bf16x8 k01 = *(const bf16x8*)&lK[lr * 64 + 32 + kg * 8];
      s0 = __builtin_amdgcn_mfma_f32_16x16x32_bf16(qf0, k00, s0, 0, 0, 0);
      s0 = __builtin_amdgcn_mfma_f32_16x16x32_bf16(qf1, k01, s0, 0, 0, 0);
      bf16x8 k10 = *(const bf16x8*)&lK[(16 + lr) * 64 + kg * 8];
      bf16x8 k11 = *(const bf16x8*)&lK[(16 + lr) * 64 + 32 + kg * 8];
      s1 = __builtin_amdgcn_mfma_f32_16x16x32_bf16(qf0, k10, s1, 0, 0, 0);
      s1 = __builtin_amdgcn_mfma_f32_16x16x32_bf16(qf1, k11, s1, 0, 0, 0);
    }
    // online softmax; D layout: row = kg*4+i, col = lr
#pragma unroll
    for (int i = 0; i < 4; ++i) {
      float a = s0[i] * 0.125f, b = s1[i] * 0.125f;
      const int q_i = qg + i;
      if (kt + lr > q_i)      a = -1e30f;
      if (kt + 16 + lr > q_i) b = -1e30f;
      float mx = fmaxf(a, b);
#pragma unroll
      for (int d = 1; d < 16; d <<= 1) mx = fmaxf(mx, __shfl_xor(mx, d, 64));
      const float mn = fmaxf(mrow[i], mx);
      const float scl = __expf(mrow[i] - mn);
      const float p0 = __expf(a - mn);
      const float p1 = __expf(b - mn);
      float ps = p0 + p1;
#pragma unroll
      for (int d = 1; d < 16; d <<= 1) ps += __shfl_xor(ps, d, 64);
      lsum[i] = lsum[i] * scl + ps;
      mrow[i] = mn;
      o[0][i] *= scl; o[1][i] *= scl; o[2][i] *= scl; o[3][i] *= scl;
      lP[w][(kg * 4 + i) * 32 + lr] = (__bf16)p0;
      lP[w][(kg * 4 + i) * 32 + 16 + lr] = (__bf16)p1;
    }
    // P (A-frag) x V  -> O   (per-wave LDS region; compiler orders ds write->read)
    bf16x8 pf = *(const bf16x8*)&lP[w][lr * 32 + kg * 8];
#pragma unroll
    for (int cf = 0; cf < 4; ++cf) {
      bf16x8 vf = *(const bf16x8*)&lV[(cf * 16 + lr) * 32 + kg * 8];
      o[cf] = __builtin_amdgcn_mfma_f32_16x16x32_bf16(pf, vf, o[cf], 0, 0, 0);
    }
  }
  float* yp = y + ((long)bI * 1024 + qt * 64 + w * 16 + kg * 4) * 1024 + h * 64 + lr;
#pragma unroll
  for (int i = 0; i < 4; ++i) {
    const float inv = 1.0f / lsum[i];
#pragma unroll
    for (int cf = 0; cf < 4; ++cf)
      yp[(long)i * 1024 + cf * 16] = o[cf][i] * inv;
  }
}

// ---------------- reduces ----------------
// x = x + xb + b2[c] + sum_z partial[z]   (2048x1024, float4)
__global__ __launch_bounds__(256) void red_mlp_k(const float* __restrict__ part,
                                                 float* __restrict__ x,
                                                 const float* __restrict__ xb,
                                                 const float* __restrict__ b2) {
  const int i = blockIdx.x * 256 + threadIdx.x;  // 0..524287
  const f32x4* p = (const f32x4*)part;
  f32x4 v = ((const f32x4*)x)[i] + ((const f32x4*)xb)[i] + ((const f32x4*)b2)[i & 255]
          + p[i] + p[i + 524288] + p[i + 2 * 524288] + p[i + 3 * 524288];
  ((f32x4*)x)[i] = v;
}

// out = b_out[c] + sum_z partial[z]   (2048x128, float4)
__global__ __launch_bounds__(256) void red_out_k(const float* __restrict__ part,
                                                 const float* __restrict__ bo,
                                                 float* __restrict__ out) {
  const int i = blockIdx.x * 256 + threadIdx.x;  // 0..65535
  const f32x4* p = (const f32x4*)part;
  f32x4 v = ((const f32x4*)bo)[i & 31]
          + p[i] + p[i + 65536] + p[i + 2 * 65536] + p[i + 3 * 65536];
  ((f32x4*)out)[i] = v;
}

// ---------------- driver ----------------
extern "C" void kernel_launch(void* const* d_in, const int* in_sizes, int n_in,
                              void* d_out, int out_size, void* d_ws, size_t ws_size,
                              hipStream_t stream) {
  (void)in_sizes; (void)n_in; (void)out_size; (void)ws_size;
  const int*   bytes = (const int*)  d_in[0];
  const float* Wtok  = (const float*)d_in[1];
  const float* Wpos  = (const float*)d_in[2];
  const float* Wqkv  = (const float*)d_in[3];
  const float* ln1g  = (const float*)d_in[4];
  const float* ln1b  = (const float*)d_in[5];
  const float* ln2g  = (const float*)d_in[6];
  const float* ln2b  = (const float*)d_in[7];
  const float* W1    = (const float*)d_in[8];
  const float* b1    = (const float*)d_in[9];
  const float* W2    = (const float*)d_in[10];
  const float* b2    = (const float*)d_in[11];
  const float* lnfg  = (const float*)d_in[12];
  const float* lnfb  = (const float*)d_in[13];
  const float* Wout  = (const float*)d_in[14];
  const float* bout  = (const float*)d_in[15];
  float* out = (float*)d_out;

  // workspace carve (total ~110.3 MB)
  char* ws = (char*)d_ws;
  float*  x    = (float*) (ws + 0);         //  8 MB  f32 residual stream
  float*  xb   = (float*) (ws + 8388608);   //  8 MB  f32 x + attn
  float*  yb   = (float*) (ws + 16777216);  //  8 MB  f32 attention out
  __bf16* h    = (__bf16*)(ws + 25165824);  //  4 MB  bf16 LN output
  __bf16* qkv  = (__bf16*)(ws + 29360128);  // 12 MB  bf16 qkv
  __bf16* mb   = (__bf16*)(ws + 41943040);  // 16 MB  bf16 MLP hidden
  __bf16* wqb  = (__bf16*)(ws + 58720256);  //  6 MB  bf16 Wqkv (layer)
  __bf16* w1b  = (__bf16*)(ws + 65011712);  //  8 MB  bf16 W1 (layer)
  __bf16* w2b  = (__bf16*)(ws + 73400320);  //  8 MB  bf16 W2 (layer)
  __bf16* wob  = (__bf16*)(ws + 81788928);  // .25 MB bf16 W_out
  float*  part = (float*) (ws + 82051072);  // 32 MB  f32 split-K partials

  embed_k<<<2048, 256, 0, stream>>>(bytes, Wtok, Wpos, x);
  cvt_k<<<128, 256, 0, stream>>>(Wout, wob, 32768);
  for (int lay = 0; lay < 8; ++lay) {
    cvt3_k<<<11264, 256, 0, stream>>>(Wqkv + (long)lay * 3145728,
                                      W1 + (long)lay * 4194304,
                                      W2 + (long)lay * 4194304, wqb, w1b, w2b);
    ln_k<false><<<2048, 256, 0, stream>>>(x, nullptr, ln1g + lay * 1024, ln1b + lay * 1024, h, nullptr);
    gemm_k<0, 1><<<dim3(16, 48, 1), 256, 0, stream>>>(h, wqb, nullptr, qkv, nullptr, 2048, 3072, 1024);
    attn_k<<<dim3(16, 32, 1), 256, 0, stream>>>(qkv, yb);
    ln_k<true><<<2048, 256, 0, stream>>>(x, yb, ln2g + lay * 1024, ln2b + lay * 1024, h, xb);
    gemm_k<1, 1><<<dim3(16, 64, 1), 256, 0, stream>>>(h, w1b, b1 + lay * 4096, mb, nullptr, 2048, 4096, 1024);
    gemm_k<2, 4><<<dim3(16, 16, 4), 256, 0, stream>>>(mb, w2b, nullptr, nullptr, part, 2048, 1024, 4096);
    red_mlp_k<<<2048, 256, 0, stream>>>(part, x, xb, b2 + lay * 1024);
  }
  ln_k<false><<<2048, 256, 0, stream>>>(x, nullptr, lnfg, lnfb, h, nullptr);
  gemm_k<2, 4><<<dim3(16, 2, 4), 256, 0, stream>>>(h, wob, nullptr, nullptr, part, 2048, 128, 1024);
  red_out_k<<<256, 256, 0, stream>>>(part, bout, out);
}